// Round 1
// baseline (1471.487 us; speedup 1.0000x reference)
//
#include <hip/hip_runtime.h>
#include <hip/hip_bf16.h>
#include <stdint.h>

// Problem constants (LSTM_36825049596199)
#define B_    64
#define T_    512
#define EMB_  128
#define H_    128
#define G4    512            // 4*H
#define M_    (B_ * T_)      // 32768 rows for the input-projection GEMM

typedef __attribute__((ext_vector_type(8))) short  short8;   // 8 bf16 (4 VGPRs) MFMA frag
typedef __attribute__((ext_vector_type(4))) float  floatx4;  // MFMA acc frag

#define GLDS(g, l) __builtin_amdgcn_global_load_lds( \
    (__attribute__((address_space(1))) void*)(g),    \
    (__attribute__((address_space(3))) void*)(l), 16, 0, 0)

__device__ __forceinline__ unsigned short f2bf_bits(float f) {
  __hip_bfloat16 h = __float2bfloat16(f);
  return *reinterpret_cast<unsigned short*>(&h);
}
__device__ __forceinline__ float bf_bits2f(unsigned short u) {
  unsigned int x = ((unsigned int)u) << 16;
  return __uint_as_float(x);
}
__device__ __forceinline__ float sigm(float x) {
  return __fdividef(1.0f, 1.0f + __expf(-x));
}
__device__ __forceinline__ float tanh_fast(float x) {
  // tanh(x) = 1 - 2/(e^{2x}+1); saturates correctly at +-inf
  return 1.0f - __fdividef(2.0f, __expf(2.0f * x) + 1.0f);
}

// xg element type is templated: float (precise) if workspace allows, bf16 otherwise.
__device__ __forceinline__ void  store_xg(float* p, float v)  { *p = v; }
__device__ __forceinline__ void  store_xg(unsigned short* p, float v) { *p = f2bf_bits(v); }
__device__ __forceinline__ float load_xg(const float* p)  { return *p; }
__device__ __forceinline__ float load_xg(const unsigned short* p) { return bf_bits2f(*p); }

// ---------------------------------------------------------------------------
// Embedding gather: x0[b,t,:] = bf16(emb[X[b,t],:]).  float4 in, ushort4 out.
__global__ void k_gather(const int* __restrict__ X, const float* __restrict__ emb,
                         unsigned short* __restrict__ x0) {
  int i = blockIdx.x * 256 + threadIdx.x;       // over M_*32 float4 groups
  int row = i >> 5, c4 = i & 31;
  float4 v = ((const float4*)emb)[(size_t)X[row] * 32 + c4];
  ushort4 o;
  o.x = f2bf_bits(v.x); o.y = f2bf_bits(v.y); o.z = f2bf_bits(v.z); o.w = f2bf_bits(v.w);
  ((ushort4*)x0)[i] = o;
}

// Per-layer weight prep: w_ih -> bf16, bias_sum = b_ih + b_hh.
__global__ void k_prep(const float* __restrict__ w, const float* __restrict__ bi,
                       const float* __restrict__ bh, unsigned short* __restrict__ wb,
                       float* __restrict__ bias, int nw) {
  int i = blockIdx.x * blockDim.x + threadIdx.x;
  int stride = gridDim.x * blockDim.x;
  for (int k = i; k < nw; k += stride) wb[k] = f2bf_bits(w[k]);
  for (int k = i; k < 2 * G4; k += stride) bias[k] = bi[k] + bh[k];
}

// ---------------------------------------------------------------------------
// Input-projection GEMM (NT): xg[dir][m][n] = sum_k A[m][k]*W[dir][n][k] + bias[dir][n]
// 128x128 tile, BK=32, 256 threads (4 waves, each owning a 64x64 quadrant of 16
// mfma_f32_16x16x32_bf16 frags). global_load_lds width-16 staging; k-chunk XOR
// swizzle (quad ^= (row>>2)&3) so ds_read_b128 frag reads are 2-way (free).
template <typename XG_T>
__global__ __launch_bounds__(256, 2) void k_gemm(
    const unsigned short* __restrict__ A,   // [M_, K] bf16 row-major
    const unsigned short* __restrict__ W,   // [2][G4][K] bf16 row-major
    const float* __restrict__ bias,         // [2][G4]
    XG_T* __restrict__ xg,                  // [2][M_][G4]
    int K) {
  __shared__ unsigned short sA[128 * 32];
  __shared__ unsigned short sB[128 * 32];
  const int tid  = threadIdx.x;
  const int lane = tid & 63;
  const int wave = tid >> 6;
  const int mt = blockIdx.x, nt = blockIdx.y, dir = blockIdx.z;
  const size_t Arow0 = (size_t)mt * 128;
  const int    Ncol0 = nt * 128;
  const unsigned short* Wd = W + (size_t)dir * G4 * K;

  const int srow = tid >> 2;                           // LDS row (issue 0), +64 for issue 1
  const int qlog = (tid & 3) ^ ((tid >> 4) & 3);       // swizzled logical k-chunk to fetch
  // Wave-uniform LDS bases (HW scatters lane i at base + i*16B)
  auto ldsA0 = (__attribute__((address_space(3))) void*)(sA + wave * 512);
  auto ldsA1 = (__attribute__((address_space(3))) void*)(sA + 2048 + wave * 512);
  auto ldsB0 = (__attribute__((address_space(3))) void*)(sB + wave * 512);
  auto ldsB1 = (__attribute__((address_space(3))) void*)(sB + 2048 + wave * 512);

  floatx4 acc[4][4];
#pragma unroll
  for (int i = 0; i < 4; ++i)
#pragma unroll
    for (int j = 0; j < 4; ++j) acc[i][j] = (floatx4)0.0f;

  const int wrow = (wave >> 1) * 64, wcol = (wave & 1) * 64;
  const int frow = lane & 15;
  const int fq   = lane >> 4;

  for (int kt = 0; kt < K; kt += 32) {
    const unsigned short* gA0 = A  + (Arow0 + srow) * (size_t)K + kt + qlog * 8;
    const unsigned short* gB0 = Wd + (size_t)(Ncol0 + srow) * K + kt + qlog * 8;
    GLDS(gA0, ldsA0);
    GLDS(gA0 + (size_t)64 * K, ldsA1);
    GLDS(gB0, ldsB0);
    GLDS(gB0 + (size_t)64 * K, ldsB1);
    __syncthreads();   // drains vmcnt -> staged data visible

    short8 af[4], bf[4];
#pragma unroll
    for (int i = 0; i < 4; ++i) {
      int r  = wrow + 16 * i + frow;
      int rn = wcol + 16 * i + frow;
      af[i] = *(const short8*)(sA + r  * 32 + ((fq ^ ((r  >> 2) & 3)) * 8));
      bf[i] = *(const short8*)(sB + rn * 32 + ((fq ^ ((rn >> 2) & 3)) * 8));
    }
#pragma unroll
    for (int i = 0; i < 4; ++i)
#pragma unroll
      for (int j = 0; j < 4; ++j)
        acc[i][j] = __builtin_amdgcn_mfma_f32_16x16x32_bf16(af[i], bf[j], acc[i][j], 0, 0, 0);
    __syncthreads();   // all waves done reading before next-tile overwrite
  }

  // Epilogue: C/D layout col=lane&15, row=(lane>>4)*4+reg  [m89-verified]
  const int r0 = (lane >> 4) * 4;
  const int cc = lane & 15;
  XG_T* xgd = xg + (size_t)dir * M_ * G4;
#pragma unroll
  for (int j = 0; j < 4; ++j) {
    int gcol = Ncol0 + wcol + 16 * j + cc;
    float bs = bias[dir * G4 + gcol];
#pragma unroll
    for (int i = 0; i < 4; ++i) {
      size_t rowb = Arow0 + wrow + 16 * i + r0;
#pragma unroll
      for (int r = 0; r < 4; ++r)
        store_xg(&xgd[(rowb + r) * G4 + gcol], acc[i][j][r] + bs);
    }
  }
}

// ---------------------------------------------------------------------------
// Recurrent scan, one block per (dir, b). 512 threads: thread (p=tid>>7, u=tid&127)
// holds W_hh rows {g*128+u : g=0..3}, k in [32p,32p+32) -> 128 fp32 weights in VGPRs.
// Per step: 8 broadcast ds_read_b128 of h, 128 FMAs (16 independent chains),
// partial-sum exchange through LDS, threads<128 do gates+state. fp32 state.
template <typename XG_T>
__global__ __launch_bounds__(512, 2) void k_scan(
    const float* __restrict__ Whh,   // [2][G4][H_]
    const float* __restrict__ hx0,   // [2][B_][H_] (layer base)
    const float* __restrict__ cx0,
    const XG_T* __restrict__ xg,     // [2][M_][G4]
    unsigned short* __restrict__ y)  // [B_][T_][2*H_] bf16
{
  const int b   = blockIdx.x & 63;
  const int dir = blockIdx.x >> 6;
  const int tid = threadIdx.x;
  const int p = tid >> 7;
  const int u = tid & 127;
  __shared__ __align__(16) float h_lds[H_];
  __shared__ float part[4][4][H_];   // [p][gate][unit]

  float4 w[4][8];
#pragma unroll
  for (int g = 0; g < 4; ++g) {
    const float* wr = Whh + ((size_t)dir * G4 + g * H_ + u) * H_ + p * 32;
#pragma unroll
    for (int q = 0; q < 8; ++q) w[g][q] = *(const float4*)(wr + q * 4);
  }

  float c = 0.0f;
  if (tid < H_) {
    h_lds[u] = hx0[(size_t)dir * B_ * H_ + b * H_ + u];
    c        = cx0[(size_t)dir * B_ * H_ + b * H_ + u];
  }
  const XG_T* xgb = xg + ((size_t)dir * M_ + (size_t)b * T_) * G4;

  float xi = 0, xf = 0, xgg = 0, xo = 0;   // prefetched xg for current step
  {
    int tt0 = dir ? (T_ - 1) : 0;
    if (tid < H_) {
      const XG_T* r = xgb + (size_t)tt0 * G4;
      xi = load_xg(r + u); xf = load_xg(r + H_ + u);
      xgg = load_xg(r + 2 * H_ + u); xo = load_xg(r + 3 * H_ + u);
    }
  }
  __syncthreads();

  for (int t = 0; t < T_; ++t) {
    // prefetch next step's xg (hides HBM/L3 latency behind this step's compute)
    float ni = 0, nf = 0, ng = 0, no = 0;
    if (t + 1 < T_ && tid < H_) {
      int ttn = dir ? (T_ - 2 - t) : (t + 1);
      const XG_T* r = xgb + (size_t)ttn * G4;
      ni = load_xg(r + u); nf = load_xg(r + H_ + u);
      ng = load_xg(r + 2 * H_ + u); no = load_xg(r + 3 * H_ + u);
    }

    const float4* h4 = ((const float4*)h_lds) + p * 8;
    float s0 = 0, s1 = 0, s2 = 0, s3 = 0;
#pragma unroll
    for (int q = 0; q < 8; ++q) {
      float4 hv = h4[q];     // wave-uniform address -> LDS broadcast (conflict-free)
      s0 = fmaf(w[0][q].x, hv.x, s0); s0 = fmaf(w[0][q].y, hv.y, s0);
      s0 = fmaf(w[0][q].z, hv.z, s0); s0 = fmaf(w[0][q].w, hv.w, s0);
      s1 = fmaf(w[1][q].x, hv.x, s1); s1 = fmaf(w[1][q].y, hv.y, s1);
      s1 = fmaf(w[1][q].z, hv.z, s1); s1 = fmaf(w[1][q].w, hv.w, s1);
      s2 = fmaf(w[2][q].x, hv.x, s2); s2 = fmaf(w[2][q].y, hv.y, s2);
      s2 = fmaf(w[2][q].z, hv.z, s2); s2 = fmaf(w[2][q].w, hv.w, s2);
      s3 = fmaf(w[3][q].x, hv.x, s3); s3 = fmaf(w[3][q].y, hv.y, s3);
      s3 = fmaf(w[3][q].z, hv.z, s3); s3 = fmaf(w[3][q].w, hv.w, s3);
    }
    part[p][0][u] = s0; part[p][1][u] = s1; part[p][2][u] = s2; part[p][3][u] = s3;
    __syncthreads();

    if (tid < H_) {
      int tt = dir ? (T_ - 1 - t) : t;
      float gi = part[0][0][u] + part[1][0][u] + part[2][0][u] + part[3][0][u] + xi;
      float gf = part[0][1][u] + part[1][1][u] + part[2][1][u] + part[3][1][u] + xf;
      float gg = part[0][2][u] + part[1][2][u] + part[2][2][u] + part[3][2][u] + xgg;
      float go = part[0][3][u] + part[1][3][u] + part[2][3][u] + part[3][3][u] + xo;
      float iv = sigm(gi), fv = sigm(gf), gv = tanh_fast(gg), ov = sigm(go);
      c = fmaf(fv, c, iv * gv);
      float h = ov * tanh_fast(c);
      h_lds[u] = h;
      y[((size_t)b * T_ + tt) * (2 * H_) + dir * H_ + u] = f2bf_bits(h);
    }
    __syncthreads();
    xi = ni; xf = nf; xgg = ng; xo = no;
  }
}

// ---------------------------------------------------------------------------
// Head: out[b] = y2[b, T-1, :] . lin_w + lin_b   (64 outputs)
__global__ void k_head(const unsigned short* __restrict__ y2, const float* __restrict__ lw,
                       const float* __restrict__ lb, float* __restrict__ out) {
  int b = blockIdx.x, l = threadIdx.x;   // 64 threads = 1 wave
  const unsigned short* row = y2 + ((size_t)b * T_ + (T_ - 1)) * (2 * H_);
  float s = 0;
#pragma unroll
  for (int k = 0; k < 4; ++k) s += bf_bits2f(row[l + 64 * k]) * lw[l + 64 * k];
#pragma unroll
  for (int off = 32; off > 0; off >>= 1) s += __shfl_down(s, off);
  if (l == 0) out[b] = s + lb[0];
}

// ---------------------------------------------------------------------------
template <typename XG_T>
static inline void run_layers(const float* const* w_hh,
                              const unsigned short* x0,
                              unsigned short* y0, unsigned short* y1, unsigned short* y2,
                              const unsigned short* wb0, const unsigned short* wb1,
                              const unsigned short* wb2,
                              const float* bias0, const float* bias1, const float* bias2,
                              const float* hx, const float* cx,
                              XG_T* xg, hipStream_t stream) {
  dim3 gg(M_ / 128, G4 / 128, 2);
  k_gemm<XG_T><<<gg, 256, 0, stream>>>(x0, wb0, bias0, xg, EMB_);
  k_scan<XG_T><<<128, 512, 0, stream>>>(w_hh[0], hx, cx, xg, y0);
  k_gemm<XG_T><<<gg, 256, 0, stream>>>(y0, wb1, bias1, xg, 2 * H_);
  k_scan<XG_T><<<128, 512, 0, stream>>>(w_hh[1], hx + 2 * B_ * H_, cx + 2 * B_ * H_, xg, y1);
  k_gemm<XG_T><<<gg, 256, 0, stream>>>(y1, wb2, bias2, xg, 2 * H_);
  k_scan<XG_T><<<128, 512, 0, stream>>>(w_hh[2], hx + 4 * B_ * H_, cx + 4 * B_ * H_, xg, y2);
}

extern "C" void kernel_launch(void* const* d_in, const int* in_sizes, int n_in,
                              void* d_out, int out_size, void* d_ws, size_t ws_size,
                              hipStream_t stream) {
  const int*   X   = (const int*)d_in[0];
  const float* emb = (const float*)d_in[1];
  const float* hx  = (const float*)d_in[2];
  const float* cx  = (const float*)d_in[3];
  const float* lw  = (const float*)d_in[4];
  const float* lb  = (const float*)d_in[5];
  const float* w_ih[3] = {(const float*)d_in[6],  (const float*)d_in[10], (const float*)d_in[14]};
  const float* w_hh[3] = {(const float*)d_in[7],  (const float*)d_in[11], (const float*)d_in[15]};
  const float* b_ih[3] = {(const float*)d_in[8],  (const float*)d_in[12], (const float*)d_in[16]};
  const float* b_hh[3] = {(const float*)d_in[9],  (const float*)d_in[13], (const float*)d_in[17]};
  float* out = (float*)d_out;

  char* ws = (char*)d_ws;
  size_t off = 0;
  auto carve = [&](size_t bytes) {
    char* p = ws + off;
    off = (off + bytes + 255) & ~(size_t)255;
    return p;
  };
  unsigned short* x0  = (unsigned short*)carve((size_t)M_ * EMB_ * 2);
  unsigned short* y0  = (unsigned short*)carve((size_t)M_ * 2 * H_ * 2);
  unsigned short* y1  = (unsigned short*)carve((size_t)M_ * 2 * H_ * 2);
  unsigned short* y2  = (unsigned short*)carve((size_t)M_ * 2 * H_ * 2);
  unsigned short* wb0 = (unsigned short*)carve((size_t)2 * G4 * EMB_ * 2);
  unsigned short* wb1 = (unsigned short*)carve((size_t)2 * G4 * 2 * H_ * 2);
  unsigned short* wb2 = (unsigned short*)carve((size_t)2 * G4 * 2 * H_ * 2);
  float* bias0 = (float*)carve(2 * G4 * 4);
  float* bias1 = (float*)carve(2 * G4 * 4);
  float* bias2 = (float*)carve(2 * G4 * 4);
  const size_t xg_f32_bytes = (size_t)2 * M_ * G4 * 4;
  const bool use_f32 = (off + xg_f32_bytes) <= ws_size;   // prefer fp32 xg when it fits
  void* xg = carve(use_f32 ? xg_f32_bytes : xg_f32_bytes / 2);

  k_prep<<<256, 256, 0, stream>>>(w_ih[0], b_ih[0], b_hh[0], wb0, bias0, 2 * G4 * EMB_);
  k_prep<<<256, 256, 0, stream>>>(w_ih[1], b_ih[1], b_hh[1], wb1, bias1, 2 * G4 * 2 * H_);
  k_prep<<<256, 256, 0, stream>>>(w_ih[2], b_ih[2], b_hh[2], wb2, bias2, 2 * G4 * 2 * H_);
  k_gather<<<(M_ * 32) / 256, 256, 0, stream>>>(X, emb, x0);

  if (use_f32)
    run_layers<float>(w_hh, x0, y0, y1, y2, wb0, wb1, wb2, bias0, bias1, bias2,
                      hx, cx, (float*)xg, stream);
  else
    run_layers<unsigned short>(w_hh, x0, y0, y1, y2, wb0, wb1, wb2, bias0, bias1, bias2,
                               hx, cx, (unsigned short*)xg, stream);

  k_head<<<64, 64, 0, stream>>>(y2, lw, lb, out);
}